// Round 15
// baseline (200.062 us; speedup 1.0000x reference)
//
#include <hip/hip_runtime.h>
#include <hip/hip_bf16.h>

using bf16 = __hip_bfloat16;
using short8 = __attribute__((ext_vector_type(8))) short;
using f32x16 = __attribute__((ext_vector_type(16))) float;

__device__ __forceinline__ ushort f2us(float v) {
    bf16 h = __float2bfloat16(v);
    return *reinterpret_cast<ushort*>(&h);
}

#define MFMA32(a, b, c) __builtin_amdgcn_mfma_f32_32x32x16_bf16((a), (b), (c), 0, 0, 0)

__device__ __forceinline__ void gload16(const void* g, void* l) {
    __builtin_amdgcn_global_load_lds(
        (const __attribute__((address_space(1))) unsigned int*)g,
        (__attribute__((address_space(3))) unsigned int*)l, 16, 0, 0);
}

__device__ __forceinline__ int cls8(int i) {
    if (i == 0) return 0;
    if (i == 1) return 1;
    if (i == 2) return 2;
    if (i == 109) return 5;
    if (i == 110) return 6;
    if (i == 111) return 7;
    return (i & 1) ? 4 : 3;
}

// ============ k_front: conv1 (blk<1792) + codebook (blk==1792) + prepack (blk>1792) ============
__global__ __launch_bounds__(256) void k_front(const float* __restrict__ x,
                                               const float* __restrict__ w_e1,
                                               const float* __restrict__ b_e1,
                                               ushort* __restrict__ h1s,
                                               const float* __restrict__ emb,
                                               float* __restrict__ c,
                                               const float* __restrict__ w_e2,
                                               const float* __restrict__ w_e3,
                                               ushort* __restrict__ Wb2f,
                                               ushort* __restrict__ Wb3f) {
    __shared__ float wl[1024];
    __shared__ float bl[64];
    __shared__ __align__(16) char obuf[28672];
    __shared__ float sval[256];
    __shared__ int   sidx[256];
    int blk = blockIdx.x;
    int tid = threadIdx.x;

    if (blk < 1792) {
        // ---------------- conv1 (1->64, k4 s2 p1) + relu -> h1s swizzled ----------------
        int r = blk % 56, b = blk / 56;
        for (int i = tid; i < 1024; i += 256) wl[i] = w_e1[i];
        if (tid < 64) bl[tid] = b_e1[tid];
        __syncthreads();
        int g = tid >> 6;
        int q = tid & 63;
        bool act = q < 56;
        int oh = 2 * r + (q >= 28);
        int ow0 = (q % 28) * 4;

        float xv[4][10];
        const float* xb = x + (size_t)b * 50176;
        #pragma unroll
        for (int kh = 0; kh < 4; ++kh) {
            int ih = 2 * oh - 1 + kh;
            bool rok = act && (unsigned)ih < 224u;
            #pragma unroll
            for (int j = 0; j < 10; ++j) {
                int iw = 2 * ow0 - 1 + j;
                xv[kh][j] = (rok && (unsigned)iw < 224u) ? xb[ih * 224 + iw] : 0.f;
            }
        }
        float a[4][16];
        #pragma unroll
        for (int i = 0; i < 4; ++i)
            #pragma unroll
            for (int j = 0; j < 16; ++j) a[i][j] = 0.f;

        const float4* wl4 = (const float4*)wl;
        #pragma unroll
        for (int j = 0; j < 16; ++j) {
            int co = g * 16 + j;
            #pragma unroll
            for (int kh = 0; kh < 4; ++kh) {
                float4 wr = wl4[co * 4 + kh];
                #pragma unroll
                for (int i = 0; i < 4; ++i) {
                    a[i][j] += xv[kh][2*i+0]*wr.x + xv[kh][2*i+1]*wr.y
                             + xv[kh][2*i+2]*wr.z + xv[kh][2*i+3]*wr.w;
                }
            }
        }
        if (act) {
            #pragma unroll
            for (int i = 0; i < 4; ++i) {
                int ow = ow0 + i, wq = ow >> 1, pw = ow & 1;
                char* rowb = obuf + (oh & 1) * 14336 + wq * 256;
                int key = (wq & 15) << 4;
                #pragma unroll
                for (int j = 0; j < 16; ++j) {
                    int co = g * 16 + j;
                    *(ushort*)(rowb + ((pw * 128 + co * 2) ^ key)) =
                        f2us(fmaxf(a[i][j] + bl[co], 0.f));
                }
            }
        }
        __syncthreads();
        const float4* sb = (const float4*)obuf;
        for (int i = tid; i < 1792; i += 256) {
            int ph = (i >= 896) ? 1 : 0;
            float4* dst = (float4*)((char*)h1s + (((size_t)(b * 2 + ph)) * 56 + r) * 14336);
            dst[i - ph * 896] = sb[i];
        }
    } else if (blk == 1792) {
        // ---------------- codebook argmin + extract c (256-thr over 512 codes) ----------------
        int k = tid;
        float s0 = 0.f, s1 = 0.f;
        const float4* e0 = (const float4*)(emb + (size_t)k * 128);
        const float4* e1 = (const float4*)(emb + (size_t)(k + 256) * 128);
        #pragma unroll
        for (int d = 0; d < 32; ++d) {
            float4 v0 = e0[d], v1 = e1[d];
            s0 += v0.x*v0.x + v0.y*v0.y + v0.z*v0.z + v0.w*v0.w;
            s1 += v1.x*v1.x + v1.y*v1.y + v1.z*v1.z + v1.w*v1.w;
        }
        float v; int idx;
        if (s1 < s0) { v = s1; idx = k + 256; } else { v = s0; idx = k; }
        sval[k] = v; sidx[k] = idx;
        __syncthreads();
        for (int off = 128; off > 0; off >>= 1) {
            if (k < off) {
                float v2 = sval[k + off]; int i2 = sidx[k + off];
                if (v2 < sval[k] || (v2 == sval[k] && i2 < sidx[k])) { sval[k] = v2; sidx[k] = i2; }
            }
            __syncthreads();
        }
        int kmin = sidx[0];
        if (k < 128) c[k] = emb[(size_t)kmin * 128 + k];
    } else {
        // ---------------- weight prepack (MFMA-fragment order) ----------------
        int i = (blk - 1793) * 256 + tid;
        const int n2 = 131072;
        const int n3 = 147456;
        if (i < n2) {
            int j = i & 7, l = (i >> 3) & 63, ks = (i >> 9) & 3, mf = (i >> 11) & 1,
                mh = (i >> 12) & 1, tap = i >> 13;
            int co = mh * 64 + mf * 32 + (l & 31);
            int ci = ks * 16 + (l >> 5) * 8 + j;
            int kh = tap >> 2, kw = tap & 3;
            Wb2f[i] = f2us(w_e2[((co * 64 + ci) * 4 + kh) * 4 + kw]);
        } else if (i < n2 + n3) {
            int t = i - n2;
            int j = t & 7, l = (t >> 3) & 63, ks = (t >> 9) & 7, mf = (t >> 12) & 1,
                mh = (t >> 13) & 1, tap = t >> 14;
            int co = mh * 64 + mf * 32 + (l & 31);
            int ci = ks * 16 + (l >> 5) * 8 + j;
            int kh = tap / 3, kw = tap % 3;
            Wb3f[t] = f2us(w_e3[((co * 128 + ci) * 3 + kh) * 3 + kw]);
        }
    }
}

// ============ conv2 (golden r7 config) + SD3 tail blocks (r11-validated safe) ============
__global__ __launch_bounds__(256) void k_conv2_sd3(const ushort* __restrict__ h1s,
                                                   const ushort* __restrict__ Wb2f,
                                                   const float* __restrict__ bias,
                                                   ushort* __restrict__ h2s,
                                                   const float* __restrict__ w_d1,
                                                   const float* __restrict__ c,
                                                   const float* __restrict__ b_d1,
                                                   float* __restrict__ D3) {
    __shared__ __align__(16) char ldsc[6 * 14848 + 2 * 16384];
    int lin = blockIdx.x;
    int tid = threadIdx.x;
    if (lin >= 896) {
        // ---------------- SD3: D3[co][rh][rw] ----------------
        float* cl = (float*)ldsc;                 // 128
        float* part = (float*)ldsc + 128;         // 9*128
        int co = lin - 896;
        if (tid < 128) cl[tid] = c[tid];
        __syncthreads();
        if (tid < 128) {
            const float* wp = w_d1 + (co * 128 + tid) * 9;
            float cv = cl[tid];
            #pragma unroll
            for (int t = 0; t < 9; ++t) part[t * 128 + tid] = wp[t] * cv;
        }
        __syncthreads();
        for (int off = 64; off > 0; off >>= 1) {
            if (tid < off) {
                #pragma unroll
                for (int t = 0; t < 9; ++t) part[t * 128 + tid] += part[t * 128 + tid + off];
            }
            __syncthreads();
        }
        if (tid < 9) {
            int rh = tid / 3, rw = tid % 3;
            int kh0 = (rh == 0) ? 1 : 0, kh1 = (rh == 2) ? 1 : 2;
            int kw0 = (rw == 0) ? 1 : 0, kw1 = (rw == 2) ? 1 : 2;
            float a = b_d1[co];
            for (int kh = kh0; kh <= kh1; ++kh)
                for (int kw = kw0; kw <= kw1; ++kw)
                    a += part[(kh * 3 + kw) * 128];
            D3[co * 9 + tid] = a;
        }
        return;
    }
    // ---------------- conv2 body (golden 51us config, unchanged) ----------------
    int v = (lin & 7) * 112 + (lin >> 3);
    int b = v / 28, oh0 = (v % 28) * 2;
    int lane = tid & 63, wv = tid >> 6;
    int mh = wv & 1, r = wv >> 1;
    int lrow = lane & 31, khalf = lane >> 5;
    const float4 z4 = {0.f, 0.f, 0.f, 0.f};

    if (tid < 192) {
        int s = tid >> 5, rr = (tid >> 4) & 1, col = tid & 15;
        ((float4*)(ldsc + s * 14848 + rr * 57 * 256))[col] = z4;
    }
    #pragma unroll
    for (int s = 0; s < 6; ++s) {
        int ph = (s < 3) ? 0 : 1;
        int rr = (s < 3) ? (oh0 + s) : (oh0 - 4 + s);
        char* ldst = ldsc + s * 14848 + 256;
        if ((unsigned)rr < 56u) {
            const char* src = (const char*)h1s + (((size_t)(b * 2 + ph)) * 56 + rr) * 14336;
            for (int c2 = wv; c2 < 14; c2 += 4)
                gload16(src + c2 * 1024 + lane * 16, ldst + c2 * 1024);
        } else {
            for (int i = tid; i < 896; i += 256) ((float4*)ldst)[i] = z4;
        }
    }
    {
        const char* asrc = (const char*)Wb2f;
        #pragma unroll
        for (int t = 0; t < 4; ++t)
            gload16(asrc + (wv * 4 + t) * 1024 + lane * 16,
                    ldsc + 89088 + (wv * 4 + t) * 1024);
    }
    __syncthreads();

    const f32x16 vz = {0,0,0,0,0,0,0,0,0,0,0,0,0,0,0,0};
    f32x16 acc[2][2];
    #pragma unroll
    for (int cf = 0; cf < 2; ++cf)
        #pragma unroll
        for (int mf = 0; mf < 2; ++mf) acc[cf][mf] = vz;

    #pragma unroll
    for (int tap = 0; tap < 16; ++tap) {
        const char* Acur = ldsc + 89088 + (tap & 1) * 16384;
        if (tap < 15) {
            char* Anxt = ldsc + 89088 + ((tap + 1) & 1) * 16384;
            const char* asrc = (const char*)Wb2f + (size_t)(tap + 1) * 16384;
            #pragma unroll
            for (int t = 0; t < 4; ++t)
                gload16(asrc + (wv * 4 + t) * 1024 + lane * 16,
                        Anxt + (wv * 4 + t) * 1024);
        }
        short8 af[2][4];
        #pragma unroll
        for (int mf = 0; mf < 2; ++mf)
            #pragma unroll
            for (int ks = 0; ks < 4; ++ks)
                af[mf][ks] = *(const short8*)(Acur + ((mh * 2 + mf) * 4 + ks) * 1024 + lane * 16);
        const int kh = tap >> 2, kw = tap & 3;
        const int pw = (kw & 1) ? 0 : 1;
        const int wofs = (kw == 0) ? 0 : (kw == 3) ? 2 : 1;
        const int sbase = (kh == 0) ? 3 : (kh == 1) ? 0 : (kh == 2) ? 4 : 1;
        const char* slab = ldsc + (sbase + r) * 14848;
        const int colb = pw * 128 + khalf * 16;
        #pragma unroll
        for (int cf = 0; cf < 2; ++cf) {
            int wp = cf * 24 + lrow + wofs;
            int key = ((wp - 1) & 15) << 4;
            const char* rowb = slab + wp * 256;
            #pragma unroll
            for (int ks = 0; ks < 4; ++ks) {
                short8 bv = *(const short8*)(rowb + ((colb + ks * 32) ^ key));
                acc[cf][0] = MFMA32(af[0][ks], bv, acc[cf][0]);
                acc[cf][1] = MFMA32(af[1][ks], bv, acc[cf][1]);
            }
        }
        __syncthreads();
    }
    {
        char* obuf = ldsc + r * 14336;
        #pragma unroll
        for (int cf = 0; cf < 2; ++cf) {
            int ow = cf * 24 + lrow;
            if (cf == 0 || lrow >= 8) {
                char* rowb = obuf + ow * 256;
                int key = (ow & 15) << 4;
                #pragma unroll
                for (int mf = 0; mf < 2; ++mf)
                    #pragma unroll
                    for (int reg = 0; reg < 16; ++reg) {
                        int co = mh * 64 + mf * 32 + (reg & 3) + 8 * (reg >> 2) + 4 * khalf;
                        float vv = fmaxf(acc[cf][mf][reg] + bias[co], 0.f);
                        *(ushort*)(rowb + ((co * 2) ^ key)) = f2us(vv);
                    }
            }
        }
    }
    __syncthreads();
    const float4* sb = (const float4*)ldsc;
    for (int i = tid; i < 1792; i += 256) {
        int rr = (i >= 896) ? 1 : 0;
        float4* dst = (float4*)((char*)h2s + ((size_t)(b * 56) + oh0 + rr) * 14336);
        dst[i - rr * 896] = sb[i];
    }
}

// ---------------- conv3 MFMA (golden: 512 thr, 4 rows, A dbuf, fused vq) ----------------
__global__ __launch_bounds__(512, 2) void k_conv3_mfma(const ushort* __restrict__ h2s,
                                                       const ushort* __restrict__ Wb3f,
                                                       const float* __restrict__ bias,
                                                       const float* __restrict__ c,
                                                       float* __restrict__ vq_part) {
    __shared__ __align__(16) char ldsc[6 * 14848 + 2 * 32768];
    __shared__ float red[8];
    int lin = blockIdx.x;
    int v = (lin & 7) * 56 + (lin >> 3);   // 448 = 8*56
    int b = v / 14, oh0 = (v % 14) * 4;
    int tid = threadIdx.x, lane = tid & 63, wv = tid >> 6;
    int mh = wv & 1, r = wv >> 1;
    int lrow = lane & 31, khalf = lane >> 5;
    const float4 z4 = {0.f, 0.f, 0.f, 0.f};

    if (tid < 192) {
        int s = tid >> 5, rr = (tid >> 4) & 1, col = tid & 15;
        ((float4*)(ldsc + s * 14848 + rr * 57 * 256))[col] = z4;
    }
    #pragma unroll
    for (int s = 0; s < 6; ++s) {
        int rr = oh0 - 1 + s;
        char* ldst = ldsc + s * 14848 + 256;
        if ((unsigned)rr < 56u) {
            const char* src = (const char*)h2s + ((size_t)b * 56 + rr) * 14336;
            for (int c2 = wv; c2 < 14; c2 += 8)
                gload16(src + c2 * 1024 + lane * 16, ldst + c2 * 1024);
        } else {
            for (int i = tid; i < 896; i += 512) ((float4*)ldst)[i] = z4;
        }
    }
    {
        const char* asrc = (const char*)Wb3f;
        #pragma unroll
        for (int t = 0; t < 4; ++t)
            gload16(asrc + (wv * 4 + t) * 1024 + lane * 16,
                    ldsc + 89088 + (wv * 4 + t) * 1024);
    }
    __syncthreads();

    const f32x16 vz = {0,0,0,0,0,0,0,0,0,0,0,0,0,0,0,0};
    f32x16 acc[2][2];
    #pragma unroll
    for (int cf = 0; cf < 2; ++cf)
        #pragma unroll
        for (int mf = 0; mf < 2; ++mf) acc[cf][mf] = vz;

    #pragma unroll
    for (int tap = 0; tap < 9; ++tap) {
        const char* Acur = ldsc + 89088 + (tap & 1) * 32768;
        if (tap < 8) {
            char* Anxt = ldsc + 89088 + ((tap + 1) & 1) * 32768;
            const char* asrc = (const char*)Wb3f + (size_t)(tap + 1) * 32768;
            #pragma unroll
            for (int t = 0; t < 4; ++t)
                gload16(asrc + (wv * 4 + t) * 1024 + lane * 16,
                        Anxt + (wv * 4 + t) * 1024);
        }
        short8 af[2][8];
        #pragma unroll
        for (int mf = 0; mf < 2; ++mf)
            #pragma unroll
            for (int ks = 0; ks < 8; ++ks)
                af[mf][ks] = *(const short8*)(Acur + ((mh * 2 + mf) * 8 + ks) * 1024 + lane * 16);
        const int kh = tap / 3, kw = tap % 3;
        const char* slab = ldsc + (r + kh) * 14848;
        #pragma unroll
        for (int cf = 0; cf < 2; ++cf) {
            int wp = cf * 24 + lrow + kw;
            int key = ((wp - 1) & 15) << 4;
            const char* rowb = slab + wp * 256;
            #pragma unroll
            for (int ks = 0; ks < 8; ++ks) {
                short8 bv = *(const short8*)(rowb + ((khalf * 16 + ks * 32) ^ key));
                acc[cf][0] = MFMA32(af[0][ks], bv, acc[cf][0]);
                acc[cf][1] = MFMA32(af[1][ks], bv, acc[cf][1]);
            }
        }
        __syncthreads();
    }
    float ls = 0.f;
    #pragma unroll
    for (int cf = 0; cf < 2; ++cf) {
        if (cf == 0 || lrow >= 8) {
            #pragma unroll
            for (int mf = 0; mf < 2; ++mf)
                #pragma unroll
                for (int reg = 0; reg < 16; ++reg) {
                    int co = mh * 64 + mf * 32 + (reg & 3) + 8 * (reg >> 2) + 4 * khalf;
                    float z = acc[cf][mf][reg] + bias[co];
                    float d = c[co] - z;
                    ls += d * d;
                }
        }
    }
    #pragma unroll
    for (int off = 32; off > 0; off >>= 1) ls += __shfl_down(ls, off);
    if (lane == 0) red[wv] = ls;
    __syncthreads();
    if (tid == 0) {
        float t = 0.f;
        #pragma unroll
        for (int i = 0; i < 8; ++i) t += red[i];
        vq_part[v] = t;
    }
}

// ---------------- d2c (golden standalone) ----------------
__global__ __launch_bounds__(64) void k_d2c(const float* __restrict__ D3,
                                            const float* __restrict__ w_dt1,
                                            const float* __restrict__ b_dt1,
                                            float* __restrict__ d2c) {
    __shared__ float dl[1152];
    int gh = blockIdx.x, gw = blockIdx.y, co2 = threadIdx.x;
    for (int i = co2; i < 1152; i += 64) dl[i] = D3[i];
    __syncthreads();
    const int rep[8] = {0, 1, 2, 4, 3, 109, 110, 111};
    int oh = rep[gh], ow = rep[gw];
    float a = b_dt1[co2];
    #pragma unroll
    for (int th = 0; th < 2; ++th) {
        int kh = ((oh + 1) & 1) + 2 * th;
        int ih = (oh + 1 - kh) >> 1;
        if ((unsigned)ih >= 56u) continue;
        int rh = (ih == 0) ? 0 : (ih == 55) ? 2 : 1;
        #pragma unroll
        for (int tw = 0; tw < 2; ++tw) {
            int kw = ((ow + 1) & 1) + 2 * tw;
            int iw = (ow + 1 - kw) >> 1;
            if ((unsigned)iw >= 56u) continue;
            int rw = (iw == 0) ? 0 : (iw == 55) ? 2 : 1;
            float t = 0.f;
            for (int ci = 0; ci < 128; ++ci)
                t += dl[ci * 9 + rh * 3 + rw] * w_dt1[(ci * 64 + co2) * 16 + kh * 4 + kw];
            a += t;
        }
    }
    d2c[(gh * 8 + gw) * 64 + co2] = fmaxf(a, 0.f);
}

// ---------------- k_out: fused Rbuild + replicate + rec-loss (r8-r12 validated) ----------------
__global__ __launch_bounds__(256) void k_out(const float* __restrict__ d2c,
                                             const float* __restrict__ w_dt2,
                                             const float* __restrict__ b_dt2,
                                             const float* __restrict__ x,
                                             float* __restrict__ out,
                                             float* __restrict__ rec_part) {
    __shared__ float el[1024];
    int tid = threadIdx.x;
    #pragma unroll
    for (int q = 0; q < 4; ++q) {
        int id = tid * 4 + q;
        int kh = id >> 8, kw = (id >> 6) & 3, gh = (id >> 3) & 7, gw = id & 7;
        float t = 0.f;
        const float* dp = d2c + (gh * 8 + gw) * 64;
        const float* wp = w_dt2 + kh * 4 + kw;
        for (int ci = 0; ci < 64; ++ci) t += dp[ci] * wp[ci * 16];
        el[((kh * 4 + kw) * 8 + gh) * 8 + gw] = t;
    }
    __syncthreads();
    float bb = b_dt2[0];
    int base = blockIdx.x * 512 + tid;
    float v = 0.f;
    #pragma unroll
    for (int t2 = 0; t2 < 2; ++t2) {
        int i4 = base + t2 * 256;
        int s4 = i4 % 12544;
        int p0 = s4 * 4;
        int oh = p0 / 224, ow0 = p0 % 224;
        float rv[4];
        #pragma unroll
        for (int j = 0; j < 4; ++j) {
            int ow = ow0 + j;
            float a = bb;
            #pragma unroll
            for (int th = 0; th < 2; ++th) {
                int kh = ((oh + 1) & 1) + 2 * th;
                int ih = (oh + 1 - kh) >> 1;
                if ((unsigned)ih < 112u) {
                    int ch = cls8(ih);
                    #pragma unroll
                    for (int tw = 0; tw < 2; ++tw) {
                        int kw = ((ow + 1) & 1) + 2 * tw;
                        int iw = (ow + 1 - kw) >> 1;
                        if ((unsigned)iw < 112u)
                            a += el[((kh * 4 + kw) * 8 + ch) * 8 + cls8(iw)];
                    }
                }
            }
            rv[j] = a;
        }
        float4 r; r.x = rv[0]; r.y = rv[1]; r.z = rv[2]; r.w = rv[3];
        float4 xv = ((const float4*)x)[i4];
        ((float4*)out)[i4] = r;
        float dx = r.x - xv.x, dy = r.y - xv.y, dz = r.z - xv.z, dw = r.w - xv.w;
        v += dx * dx + dy * dy + dz * dz + dw * dw;
    }
    __shared__ float red[4];
    #pragma unroll
    for (int off = 32; off > 0; off >>= 1) v += __shfl_down(v, off);
    int wid = tid >> 6, lane = tid & 63;
    if (lane == 0) red[wid] = v;
    __syncthreads();
    if (tid == 0) rec_part[blockIdx.x] = red[0] + red[1] + red[2] + red[3];
}

__global__ __launch_bounds__(256) void k_fin(const float* __restrict__ vq_part,
                                             const float* __restrict__ rec_part,
                                             float* __restrict__ out, int loss_base) {
    __shared__ float sv[256], sr[256];
    float a = 0.f, b2 = 0.f;
    for (int i = threadIdx.x; i < 448; i += 256) a  += vq_part[i];
    for (int i = threadIdx.x; i < 784; i += 256) b2 += rec_part[i];
    sv[threadIdx.x] = a; sr[threadIdx.x] = b2;
    __syncthreads();
    for (int off = 128; off > 0; off >>= 1) {
        if (threadIdx.x < off) { sv[threadIdx.x] += sv[threadIdx.x + off]; sr[threadIdx.x] += sr[threadIdx.x + off]; }
        __syncthreads();
    }
    if (threadIdx.x == 0) {
        float vq  = 2.f * sv[0] / 12845056.f;
        float rec = sr[0] / 1605632.f;
        out[loss_base + 0] = rec + vq;
        out[loss_base + 1] = rec;
        out[loss_base + 2] = vq;
    }
}

extern "C" void kernel_launch(void* const* d_in, const int* in_sizes, int n_in,
                              void* d_out, int out_size, void* d_ws, size_t ws_size,
                              hipStream_t stream) {
    const float* x     = (const float*)d_in[0];
    const float* w_e1  = (const float*)d_in[1];
    const float* b_e1  = (const float*)d_in[2];
    const float* w_e2  = (const float*)d_in[3];
    const float* b_e2  = (const float*)d_in[4];
    const float* w_e3  = (const float*)d_in[5];
    const float* b_e3  = (const float*)d_in[6];
    const float* emb   = (const float*)d_in[7];
    const float* w_d1  = (const float*)d_in[8];
    const float* b_d1  = (const float*)d_in[9];
    const float* w_dt1 = (const float*)d_in[10];
    const float* b_dt1 = (const float*)d_in[11];
    const float* w_dt2 = (const float*)d_in[12];
    const float* b_dt2 = (const float*)d_in[13];
    float* out = (float*)d_out;
    float* ws  = (float*)d_ws;

    float* c        = ws + 16;
    float* D3       = ws + 256;
    float* d2c      = ws + 2048;
    float* vq_part  = ws + 65536;    // 448
    float* rec_part = ws + 69632;    // 784
    ushort* Wb2f    = (ushort*)(ws + 131072);
    ushort* Wb3f    = (ushort*)(ws + 196608);
    ushort* h1s     = (ushort*)(ws + 1310720);
    ushort* h2s     = (ushort*)(ws + 14155776);

    // 1792 conv1 + 1 codebook + 1088 prepack
    k_front<<<2881, 256, 0, stream>>>(x, w_e1, b_e1, h1s, emb, c, w_e2, w_e3, Wb2f, Wb3f);
    // 896 conv2 + 128 SD3
    k_conv2_sd3<<<1024, 256, 0, stream>>>(h1s, Wb2f, b_e2, h2s, w_d1, c, b_d1, D3);
    // golden conv3
    k_conv3_mfma<<<448, 512, 0, stream>>>(h2s, Wb3f, b_e3, c, vq_part);
    k_d2c<<<dim3(8, 8), 64, 0, stream>>>(D3, w_dt1, b_dt1, d2c);
    k_out<<<784, 256, 0, stream>>>(d2c, w_dt2, b_dt2, x, out, rec_part);
    k_fin<<<1, 256, 0, stream>>>(vq_part, rec_part, out, out_size - 3);
}

// Round 16
// 181.993 us; speedup vs baseline: 1.0993x; 1.0993x over previous
//
#include <hip/hip_runtime.h>
#include <hip/hip_bf16.h>

using bf16 = __hip_bfloat16;
using short8 = __attribute__((ext_vector_type(8))) short;
using f32x16 = __attribute__((ext_vector_type(16))) float;

__device__ __forceinline__ ushort f2us(float v) {
    bf16 h = __float2bfloat16(v);
    return *reinterpret_cast<ushort*>(&h);
}

#define MFMA32(a, b, c) __builtin_amdgcn_mfma_f32_32x32x16_bf16((a), (b), (c), 0, 0, 0)

__device__ __forceinline__ void gload16(const void* g, void* l) {
    __builtin_amdgcn_global_load_lds(
        (const __attribute__((address_space(1))) unsigned int*)g,
        (__attribute__((address_space(3))) unsigned int*)l, 16, 0, 0);
}

__device__ __forceinline__ int cls8(int i) {
    if (i == 0) return 0;
    if (i == 1) return 1;
    if (i == 2) return 2;
    if (i == 109) return 5;
    if (i == 110) return 6;
    if (i == 111) return 7;
    return (i & 1) ? 4 : 3;
}

// ---------------- codebook argmin + extract c (golden) ----------------
__global__ void k_codebook(const float* __restrict__ emb, float* __restrict__ c) {
    __shared__ float sval[512];
    __shared__ int   sidx[512];
    int k = threadIdx.x;
    float s = 0.f;
    const float4* e4 = (const float4*)(emb + k * 128);
    #pragma unroll
    for (int d = 0; d < 32; ++d) {
        float4 v = e4[d];
        s += v.x * v.x + v.y * v.y + v.z * v.z + v.w * v.w;
    }
    sval[k] = s; sidx[k] = k;
    __syncthreads();
    for (int off = 256; off > 0; off >>= 1) {
        if (k < off) {
            float v2 = sval[k + off]; int i2 = sidx[k + off];
            if (v2 < sval[k] || (v2 == sval[k] && i2 < sidx[k])) { sval[k] = v2; sidx[k] = i2; }
        }
        __syncthreads();
    }
    int kmin = sidx[0];
    if (k < 128) c[k] = emb[kmin * 128 + k];
}

// ---------------- weight prepack: MFMA-fragment order (golden) ----------------
__global__ __launch_bounds__(256) void k_prepack(const float* __restrict__ w_e2,
                                                 const float* __restrict__ w_e3,
                                                 ushort* __restrict__ Wb2f,
                                                 ushort* __restrict__ Wb3f) {
    int i = blockIdx.x * 256 + threadIdx.x;
    const int n2 = 131072;
    const int n3 = 147456;
    if (i < n2) {
        int j = i & 7, l = (i >> 3) & 63, ks = (i >> 9) & 3, mf = (i >> 11) & 1,
            mh = (i >> 12) & 1, tap = i >> 13;
        int co = mh * 64 + mf * 32 + (l & 31);
        int ci = ks * 16 + (l >> 5) * 8 + j;
        int kh = tap >> 2, kw = tap & 3;
        Wb2f[i] = f2us(w_e2[((co * 64 + ci) * 4 + kh) * 4 + kw]);
    } else if (i < n2 + n3) {
        int t = i - n2;
        int j = t & 7, l = (t >> 3) & 63, ks = (t >> 9) & 7, mf = (t >> 12) & 1,
            mh = (t >> 13) & 1, tap = t >> 14;
        int co = mh * 64 + mf * 32 + (l & 31);
        int ci = ks * 16 + (l >> 5) * 8 + j;
        int kh = tap / 3, kw = tap % 3;
        Wb3f[t] = f2us(w_e3[((co * 128 + ci) * 3 + kh) * 3 + kw]);
    }
}

// ---------------- conv1 (1->64, k4 s2 p1) + relu -> h1s swizzled (golden) ----------------
__global__ __launch_bounds__(256) void k_conv1(const float* __restrict__ x,
                                               const float* __restrict__ w,
                                               const float* __restrict__ bias,
                                               ushort* __restrict__ h1s) {
    __shared__ float wl[1024];
    __shared__ float bl[64];
    __shared__ __align__(16) char obuf[28672];
    int tid = threadIdx.x;
    for (int i = tid; i < 1024; i += 256) wl[i] = w[i];
    if (tid < 64) bl[tid] = bias[tid];
    __syncthreads();
    int r = blockIdx.x, b = blockIdx.y;
    int g = tid >> 6;
    int q = tid & 63;
    bool act = q < 56;
    int oh = 2 * r + (q >= 28);
    int ow0 = (q % 28) * 4;

    float xv[4][10];
    const float* xb = x + (size_t)b * 50176;
    #pragma unroll
    for (int kh = 0; kh < 4; ++kh) {
        int ih = 2 * oh - 1 + kh;
        bool rok = act && (unsigned)ih < 224u;
        #pragma unroll
        for (int j = 0; j < 10; ++j) {
            int iw = 2 * ow0 - 1 + j;
            xv[kh][j] = (rok && (unsigned)iw < 224u) ? xb[ih * 224 + iw] : 0.f;
        }
    }
    float a[4][16];
    #pragma unroll
    for (int i = 0; i < 4; ++i)
        #pragma unroll
        for (int j = 0; j < 16; ++j) a[i][j] = 0.f;

    const float4* wl4 = (const float4*)wl;
    #pragma unroll
    for (int j = 0; j < 16; ++j) {
        int co = g * 16 + j;
        #pragma unroll
        for (int kh = 0; kh < 4; ++kh) {
            float4 wr = wl4[co * 4 + kh];
            #pragma unroll
            for (int i = 0; i < 4; ++i) {
                a[i][j] += xv[kh][2*i+0]*wr.x + xv[kh][2*i+1]*wr.y
                         + xv[kh][2*i+2]*wr.z + xv[kh][2*i+3]*wr.w;
            }
        }
    }
    if (act) {
        #pragma unroll
        for (int i = 0; i < 4; ++i) {
            int ow = ow0 + i, wq = ow >> 1, pw = ow & 1;
            char* rowb = obuf + (oh & 1) * 14336 + wq * 256;
            int key = (wq & 15) << 4;
            #pragma unroll
            for (int j = 0; j < 16; ++j) {
                int co = g * 16 + j;
                *(ushort*)(rowb + ((pw * 128 + co * 2) ^ key)) =
                    f2us(fmaxf(a[i][j] + bl[co], 0.f));
            }
        }
    }
    __syncthreads();
    const float4* sb = (const float4*)obuf;
    for (int i = tid; i < 1792; i += 256) {
        int ph = (i >= 896) ? 1 : 0;
        float4* dst = (float4*)((char*)h1s + (((size_t)(b * 2 + ph)) * 56 + r) * 14336);
        dst[i - ph * 896] = sb[i];
    }
}

// ============ conv2 (golden config) + SD3 tail blocks (validated: conv2 body 51.1us) ============
__global__ __launch_bounds__(256) void k_conv2_sd3(const ushort* __restrict__ h1s,
                                                   const ushort* __restrict__ Wb2f,
                                                   const float* __restrict__ bias,
                                                   ushort* __restrict__ h2s,
                                                   const float* __restrict__ w_d1,
                                                   const float* __restrict__ c,
                                                   const float* __restrict__ b_d1,
                                                   float* __restrict__ D3) {
    __shared__ __align__(16) char ldsc[6 * 14848 + 2 * 16384];
    int lin = blockIdx.x;
    int tid = threadIdx.x;
    if (lin >= 896) {
        // ---------------- SD3: D3[co][rh][rw] ----------------
        float* cl = (float*)ldsc;
        float* part = (float*)ldsc + 128;
        int co = lin - 896;
        if (tid < 128) cl[tid] = c[tid];
        __syncthreads();
        if (tid < 128) {
            const float* wp = w_d1 + (co * 128 + tid) * 9;
            float cv = cl[tid];
            #pragma unroll
            for (int t = 0; t < 9; ++t) part[t * 128 + tid] = wp[t] * cv;
        }
        __syncthreads();
        for (int off = 64; off > 0; off >>= 1) {
            if (tid < off) {
                #pragma unroll
                for (int t = 0; t < 9; ++t) part[t * 128 + tid] += part[t * 128 + tid + off];
            }
            __syncthreads();
        }
        if (tid < 9) {
            int rh = tid / 3, rw = tid % 3;
            int kh0 = (rh == 0) ? 1 : 0, kh1 = (rh == 2) ? 1 : 2;
            int kw0 = (rw == 0) ? 1 : 0, kw1 = (rw == 2) ? 1 : 2;
            float a = b_d1[co];
            for (int kh = kh0; kh <= kh1; ++kh)
                for (int kw = kw0; kw <= kw1; ++kw)
                    a += part[(kh * 3 + kw) * 128];
            D3[co * 9 + tid] = a;
        }
        return;
    }
    // ---------------- conv2 body (golden, unchanged) ----------------
    int v = (lin & 7) * 112 + (lin >> 3);
    int b = v / 28, oh0 = (v % 28) * 2;
    int lane = tid & 63, wv = tid >> 6;
    int mh = wv & 1, r = wv >> 1;
    int lrow = lane & 31, khalf = lane >> 5;
    const float4 z4 = {0.f, 0.f, 0.f, 0.f};

    if (tid < 192) {
        int s = tid >> 5, rr = (tid >> 4) & 1, col = tid & 15;
        ((float4*)(ldsc + s * 14848 + rr * 57 * 256))[col] = z4;
    }
    #pragma unroll
    for (int s = 0; s < 6; ++s) {
        int ph = (s < 3) ? 0 : 1;
        int rr = (s < 3) ? (oh0 + s) : (oh0 - 4 + s);
        char* ldst = ldsc + s * 14848 + 256;
        if ((unsigned)rr < 56u) {
            const char* src = (const char*)h1s + (((size_t)(b * 2 + ph)) * 56 + rr) * 14336;
            for (int c2 = wv; c2 < 14; c2 += 4)
                gload16(src + c2 * 1024 + lane * 16, ldst + c2 * 1024);
        } else {
            for (int i = tid; i < 896; i += 256) ((float4*)ldst)[i] = z4;
        }
    }
    {
        const char* asrc = (const char*)Wb2f;
        #pragma unroll
        for (int t = 0; t < 4; ++t)
            gload16(asrc + (wv * 4 + t) * 1024 + lane * 16,
                    ldsc + 89088 + (wv * 4 + t) * 1024);
    }
    __syncthreads();

    const f32x16 vz = {0,0,0,0,0,0,0,0,0,0,0,0,0,0,0,0};
    f32x16 acc[2][2];
    #pragma unroll
    for (int cf = 0; cf < 2; ++cf)
        #pragma unroll
        for (int mf = 0; mf < 2; ++mf) acc[cf][mf] = vz;

    #pragma unroll
    for (int tap = 0; tap < 16; ++tap) {
        const char* Acur = ldsc + 89088 + (tap & 1) * 16384;
        if (tap < 15) {
            char* Anxt = ldsc + 89088 + ((tap + 1) & 1) * 16384;
            const char* asrc = (const char*)Wb2f + (size_t)(tap + 1) * 16384;
            #pragma unroll
            for (int t = 0; t < 4; ++t)
                gload16(asrc + (wv * 4 + t) * 1024 + lane * 16,
                        Anxt + (wv * 4 + t) * 1024);
        }
        short8 af[2][4];
        #pragma unroll
        for (int mf = 0; mf < 2; ++mf)
            #pragma unroll
            for (int ks = 0; ks < 4; ++ks)
                af[mf][ks] = *(const short8*)(Acur + ((mh * 2 + mf) * 4 + ks) * 1024 + lane * 16);
        const int kh = tap >> 2, kw = tap & 3;
        const int pw = (kw & 1) ? 0 : 1;
        const int wofs = (kw == 0) ? 0 : (kw == 3) ? 2 : 1;
        const int sbase = (kh == 0) ? 3 : (kh == 1) ? 0 : (kh == 2) ? 4 : 1;
        const char* slab = ldsc + (sbase + r) * 14848;
        const int colb = pw * 128 + khalf * 16;
        #pragma unroll
        for (int cf = 0; cf < 2; ++cf) {
            int wp = cf * 24 + lrow + wofs;
            int key = ((wp - 1) & 15) << 4;
            const char* rowb = slab + wp * 256;
            #pragma unroll
            for (int ks = 0; ks < 4; ++ks) {
                short8 bv = *(const short8*)(rowb + ((colb + ks * 32) ^ key));
                acc[cf][0] = MFMA32(af[0][ks], bv, acc[cf][0]);
                acc[cf][1] = MFMA32(af[1][ks], bv, acc[cf][1]);
            }
        }
        __syncthreads();
    }
    {
        char* obuf = ldsc + r * 14336;
        #pragma unroll
        for (int cf = 0; cf < 2; ++cf) {
            int ow = cf * 24 + lrow;
            if (cf == 0 || lrow >= 8) {
                char* rowb = obuf + ow * 256;
                int key = (ow & 15) << 4;
                #pragma unroll
                for (int mf = 0; mf < 2; ++mf)
                    #pragma unroll
                    for (int reg = 0; reg < 16; ++reg) {
                        int co = mh * 64 + mf * 32 + (reg & 3) + 8 * (reg >> 2) + 4 * khalf;
                        float vv = fmaxf(acc[cf][mf][reg] + bias[co], 0.f);
                        *(ushort*)(rowb + ((co * 2) ^ key)) = f2us(vv);
                    }
            }
        }
    }
    __syncthreads();
    const float4* sb = (const float4*)ldsc;
    for (int i = tid; i < 1792; i += 256) {
        int rr = (i >= 896) ? 1 : 0;
        float4* dst = (float4*)((char*)h2s + ((size_t)(b * 56) + oh0 + rr) * 14336);
        dst[i - rr * 896] = sb[i];
    }
}

// ---------------- conv3 MFMA (golden: 512 thr, 4 rows, A dbuf, fused vq) ----------------
__global__ __launch_bounds__(512, 2) void k_conv3_mfma(const ushort* __restrict__ h2s,
                                                       const ushort* __restrict__ Wb3f,
                                                       const float* __restrict__ bias,
                                                       const float* __restrict__ c,
                                                       float* __restrict__ vq_part) {
    __shared__ __align__(16) char ldsc[6 * 14848 + 2 * 32768];
    __shared__ float red[8];
    int lin = blockIdx.x;
    int v = (lin & 7) * 56 + (lin >> 3);   // 448 = 8*56
    int b = v / 14, oh0 = (v % 14) * 4;
    int tid = threadIdx.x, lane = tid & 63, wv = tid >> 6;
    int mh = wv & 1, r = wv >> 1;
    int lrow = lane & 31, khalf = lane >> 5;
    const float4 z4 = {0.f, 0.f, 0.f, 0.f};

    if (tid < 192) {
        int s = tid >> 5, rr = (tid >> 4) & 1, col = tid & 15;
        ((float4*)(ldsc + s * 14848 + rr * 57 * 256))[col] = z4;
    }
    #pragma unroll
    for (int s = 0; s < 6; ++s) {
        int rr = oh0 - 1 + s;
        char* ldst = ldsc + s * 14848 + 256;
        if ((unsigned)rr < 56u) {
            const char* src = (const char*)h2s + ((size_t)b * 56 + rr) * 14336;
            for (int c2 = wv; c2 < 14; c2 += 8)
                gload16(src + c2 * 1024 + lane * 16, ldst + c2 * 1024);
        } else {
            for (int i = tid; i < 896; i += 512) ((float4*)ldst)[i] = z4;
        }
    }
    {
        const char* asrc = (const char*)Wb3f;
        #pragma unroll
        for (int t = 0; t < 4; ++t)
            gload16(asrc + (wv * 4 + t) * 1024 + lane * 16,
                    ldsc + 89088 + (wv * 4 + t) * 1024);
    }
    __syncthreads();

    const f32x16 vz = {0,0,0,0,0,0,0,0,0,0,0,0,0,0,0,0};
    f32x16 acc[2][2];
    #pragma unroll
    for (int cf = 0; cf < 2; ++cf)
        #pragma unroll
        for (int mf = 0; mf < 2; ++mf) acc[cf][mf] = vz;

    #pragma unroll
    for (int tap = 0; tap < 9; ++tap) {
        const char* Acur = ldsc + 89088 + (tap & 1) * 32768;
        if (tap < 8) {
            char* Anxt = ldsc + 89088 + ((tap + 1) & 1) * 32768;
            const char* asrc = (const char*)Wb3f + (size_t)(tap + 1) * 32768;
            #pragma unroll
            for (int t = 0; t < 4; ++t)
                gload16(asrc + (wv * 4 + t) * 1024 + lane * 16,
                        Anxt + (wv * 4 + t) * 1024);
        }
        short8 af[2][8];
        #pragma unroll
        for (int mf = 0; mf < 2; ++mf)
            #pragma unroll
            for (int ks = 0; ks < 8; ++ks)
                af[mf][ks] = *(const short8*)(Acur + ((mh * 2 + mf) * 8 + ks) * 1024 + lane * 16);
        const int kh = tap / 3, kw = tap % 3;
        const char* slab = ldsc + (r + kh) * 14848;
        #pragma unroll
        for (int cf = 0; cf < 2; ++cf) {
            int wp = cf * 24 + lrow + kw;
            int key = ((wp - 1) & 15) << 4;
            const char* rowb = slab + wp * 256;
            #pragma unroll
            for (int ks = 0; ks < 8; ++ks) {
                short8 bv = *(const short8*)(rowb + ((khalf * 16 + ks * 32) ^ key));
                acc[cf][0] = MFMA32(af[0][ks], bv, acc[cf][0]);
                acc[cf][1] = MFMA32(af[1][ks], bv, acc[cf][1]);
            }
        }
        __syncthreads();
    }
    float ls = 0.f;
    #pragma unroll
    for (int cf = 0; cf < 2; ++cf) {
        if (cf == 0 || lrow >= 8) {
            #pragma unroll
            for (int mf = 0; mf < 2; ++mf)
                #pragma unroll
                for (int reg = 0; reg < 16; ++reg) {
                    int co = mh * 64 + mf * 32 + (reg & 3) + 8 * (reg >> 2) + 4 * khalf;
                    float z = acc[cf][mf][reg] + bias[co];
                    float d = c[co] - z;
                    ls += d * d;
                }
        }
    }
    #pragma unroll
    for (int off = 32; off > 0; off >>= 1) ls += __shfl_down(ls, off);
    if (lane == 0) red[wv] = ls;
    __syncthreads();
    if (tid == 0) {
        float t = 0.f;
        #pragma unroll
        for (int i = 0; i < 8; ++i) t += red[i];
        vq_part[v] = t;
    }
}

// ---------------- d2c (golden) ----------------
__global__ __launch_bounds__(64) void k_d2c(const float* __restrict__ D3,
                                            const float* __restrict__ w_dt1,
                                            const float* __restrict__ b_dt1,
                                            float* __restrict__ d2c) {
    __shared__ float dl[1152];
    int gh = blockIdx.x, gw = blockIdx.y, co2 = threadIdx.x;
    for (int i = co2; i < 1152; i += 64) dl[i] = D3[i];
    __syncthreads();
    const int rep[8] = {0, 1, 2, 4, 3, 109, 110, 111};
    int oh = rep[gh], ow = rep[gw];
    float a = b_dt1[co2];
    #pragma unroll
    for (int th = 0; th < 2; ++th) {
        int kh = ((oh + 1) & 1) + 2 * th;
        int ih = (oh + 1 - kh) >> 1;
        if ((unsigned)ih >= 56u) continue;
        int rh = (ih == 0) ? 0 : (ih == 55) ? 2 : 1;
        #pragma unroll
        for (int tw = 0; tw < 2; ++tw) {
            int kw = ((ow + 1) & 1) + 2 * tw;
            int iw = (ow + 1 - kw) >> 1;
            if ((unsigned)iw >= 56u) continue;
            int rw = (iw == 0) ? 0 : (iw == 55) ? 2 : 1;
            float t = 0.f;
            for (int ci = 0; ci < 128; ++ci)
                t += dl[ci * 9 + rh * 3 + rw] * w_dt1[(ci * 64 + co2) * 16 + kh * 4 + kw];
            a += t;
        }
    }
    d2c[(gh * 8 + gw) * 64 + co2] = fmaxf(a, 0.f);
}

// ---------------- Rbuild (golden) ----------------
__global__ __launch_bounds__(256) void k_Rbuild(const float* __restrict__ d2c,
                                                const float* __restrict__ w_dt2,
                                                const float* __restrict__ b_dt2,
                                                float* __restrict__ R) {
    __shared__ float el[1024];
    int tid = threadIdx.x;
    #pragma unroll
    for (int q = 0; q < 4; ++q) {
        int id = tid * 4 + q;
        int kh = id >> 8, kw = (id >> 6) & 3, gh = (id >> 3) & 7, gw = id & 7;
        float t = 0.f;
        const float* dp = d2c + (gh * 8 + gw) * 64;
        const float* wp = w_dt2 + kh * 4 + kw;
        for (int ci = 0; ci < 64; ++ci) t += dp[ci] * wp[ci * 16];
        el[((kh * 4 + kw) * 8 + gh) * 8 + gw] = t;
    }
    __syncthreads();
    int s = blockIdx.x * 256 + tid;
    int oh = s / 224, ow = s % 224;
    float a = b_dt2[0];
    #pragma unroll
    for (int th = 0; th < 2; ++th) {
        int kh = ((oh + 1) & 1) + 2 * th;
        int ih = (oh + 1 - kh) >> 1;
        if ((unsigned)ih >= 112u) continue;
        int ch = cls8(ih);
        #pragma unroll
        for (int tw = 0; tw < 2; ++tw) {
            int kw = ((ow + 1) & 1) + 2 * tw;
            int iw = (ow + 1 - kw) >> 1;
            if ((unsigned)iw >= 112u) continue;
            int cw = cls8(iw);
            a += el[((kh * 4 + kw) * 8 + ch) * 8 + cw];
        }
    }
    R[s] = a;
}

// ---------------- replicate + rec-loss (golden) ----------------
__global__ __launch_bounds__(256) void k_out(const float* __restrict__ R,
                                             const float* __restrict__ x,
                                             float* __restrict__ out,
                                             float* __restrict__ rec_part) {
    int base = blockIdx.x * 512 + threadIdx.x;
    float v = 0.f;
    #pragma unroll
    for (int t = 0; t < 2; ++t) {
        int i4 = base + t * 256;
        int s4 = i4 % 12544;
        float4 r = ((const float4*)R)[s4];
        float4 xv = ((const float4*)x)[i4];
        ((float4*)out)[i4] = r;
        float dx = r.x - xv.x, dy = r.y - xv.y, dz = r.z - xv.z, dw = r.w - xv.w;
        v += dx * dx + dy * dy + dz * dz + dw * dw;
    }
    __shared__ float red[4];
    #pragma unroll
    for (int off = 32; off > 0; off >>= 1) v += __shfl_down(v, off);
    int wid = threadIdx.x >> 6, lane = threadIdx.x & 63;
    if (lane == 0) red[wid] = v;
    __syncthreads();
    if (threadIdx.x == 0) rec_part[blockIdx.x] = red[0] + red[1] + red[2] + red[3];
}

__global__ __launch_bounds__(256) void k_fin(const float* __restrict__ vq_part,
                                             const float* __restrict__ rec_part,
                                             float* __restrict__ out, int loss_base) {
    __shared__ float sv[256], sr[256];
    float a = 0.f, b2 = 0.f;
    for (int i = threadIdx.x; i < 448; i += 256) a  += vq_part[i];
    for (int i = threadIdx.x; i < 784; i += 256) b2 += rec_part[i];
    sv[threadIdx.x] = a; sr[threadIdx.x] = b2;
    __syncthreads();
    for (int off = 128; off > 0; off >>= 1) {
        if (threadIdx.x < off) { sv[threadIdx.x] += sv[threadIdx.x + off]; sr[threadIdx.x] += sr[threadIdx.x + off]; }
        __syncthreads();
    }
    if (threadIdx.x == 0) {
        float vq  = 2.f * sv[0] / 12845056.f;
        float rec = sr[0] / 1605632.f;
        out[loss_base + 0] = rec + vq;
        out[loss_base + 1] = rec;
        out[loss_base + 2] = vq;
    }
}

extern "C" void kernel_launch(void* const* d_in, const int* in_sizes, int n_in,
                              void* d_out, int out_size, void* d_ws, size_t ws_size,
                              hipStream_t stream) {
    const float* x     = (const float*)d_in[0];
    const float* w_e1  = (const float*)d_in[1];
    const float* b_e1  = (const float*)d_in[2];
    const float* w_e2  = (const float*)d_in[3];
    const float* b_e2  = (const float*)d_in[4];
    const float* w_e3  = (const float*)d_in[5];
    const float* b_e3  = (const float*)d_in[6];
    const float* emb   = (const float*)d_in[7];
    const float* w_d1  = (const float*)d_in[8];
    const float* b_d1  = (const float*)d_in[9];
    const float* w_dt1 = (const float*)d_in[10];
    const float* b_dt1 = (const float*)d_in[11];
    const float* w_dt2 = (const float*)d_in[12];
    const float* b_dt2 = (const float*)d_in[13];
    float* out = (float*)d_out;
    float* ws  = (float*)d_ws;

    float* c        = ws + 16;
    float* D3       = ws + 256;
    float* d2c      = ws + 2048;
    float* R        = ws + 8192;
    float* vq_part  = ws + 65536;    // 448
    float* rec_part = ws + 69632;    // 784
    ushort* Wb2f    = (ushort*)(ws + 131072);
    ushort* Wb3f    = (ushort*)(ws + 196608);
    ushort* h1s     = (ushort*)(ws + 1310720);
    ushort* h2s     = (ushort*)(ws + 14155776);

    k_codebook<<<1, 512, 0, stream>>>(emb, c);
    k_prepack<<<1088, 256, 0, stream>>>(w_e2, w_e3, Wb2f, Wb3f);
    k_conv1<<<dim3(56, 32), 256, 0, stream>>>(x, w_e1, b_e1, h1s);
    // 896 conv2 + 128 SD3 tail blocks (one launch saved)
    k_conv2_sd3<<<1024, 256, 0, stream>>>(h1s, Wb2f, b_e2, h2s, w_d1, c, b_d1, D3);
    k_conv3_mfma<<<448, 512, 0, stream>>>(h2s, Wb3f, b_e3, c, vq_part);
    k_d2c<<<dim3(8, 8), 64, 0, stream>>>(D3, w_dt1, b_dt1, d2c);
    k_Rbuild<<<196, 256, 0, stream>>>(d2c, w_dt2, b_dt2, R);
    k_out<<<784, 256, 0, stream>>>(R, x, out, rec_part);
    k_fin<<<1, 256, 0, stream>>>(vq_part, rec_part, out, out_size - 3);
}